// Round 3
// baseline (537.307 us; speedup 1.0000x reference)
//
#include <hip/hip_runtime.h>
#include <math.h>

typedef __attribute__((ext_vector_type(8))) short bf16x8;
typedef __attribute__((ext_vector_type(8))) unsigned short u16x8;
typedef __attribute__((ext_vector_type(4))) float f32x4;

__device__ __forceinline__ unsigned short f2bf(float f) {
  unsigned u = __float_as_uint(f);
  return (unsigned short)((u + 0x7FFFu + ((u >> 16) & 1u)) >> 16);
}
__device__ __forceinline__ float bf2f(unsigned short h) {
  return __uint_as_float(((unsigned)h) << 16);
}
__device__ __forceinline__ void cvt8(const float4& a, const float4& b,
                                     u16x8& h, u16x8& l) {
  float f[8] = {a.x, a.y, a.z, a.w, b.x, b.y, b.z, b.w};
#pragma unroll
  for (int i = 0; i < 8; ++i) {
    unsigned short hh = f2bf(f[i]);
    h[i] = hh;
    l[i] = f2bf(f[i] - bf2f(hh));
  }
}

// ---------------------------------------------------------------------------
// K0: transpose+split Wp [1024][128] fp32 -> k-major bf16 tiles
//     th/tl layout: [kt 0..15][kg 0..7][col 0..127][e 0..7]   (k' = kg*8+e)
// ---------------------------------------------------------------------------
__global__ __launch_bounds__(256) void caps_prep(
    const float* __restrict__ Wp, unsigned short* __restrict__ th,
    unsigned short* __restrict__ tl)
{
  __shared__ float tile[64][128];
  const int t = threadIdx.x, b = blockIdx.x;
  const float* src = Wp + (size_t)b * 64 * 128;
#pragma unroll
  for (int i = 0; i < 8; ++i) {
    int j = t + i * 256;
    int kk = j >> 5, q = j & 31;
    *(float4*)&tile[kk][q * 4] = *(const float4*)(src + kk * 128 + q * 4);
  }
  __syncthreads();
  const int col = t >> 1, kg0 = (t & 1) * 4;   // this thread: k' = kg0*8 .. +31
  unsigned short hi[32], lo[32];
#pragma unroll
  for (int kk = 0; kk < 32; ++kk) {
    float v = tile[kg0 * 8 + kk][col];
    unsigned short h = f2bf(v);
    hi[kk] = h;
    lo[kk] = f2bf(v - bf2f(h));
  }
#pragma unroll
  for (int i = 0; i < 4; ++i) {
    size_t off = (size_t)b * 8192 + (size_t)(kg0 + i) * 1024 + (size_t)col * 8;
    u16x8 vh, vl;
#pragma unroll
    for (int e = 0; e < 8; ++e) { vh[e] = hi[i * 8 + e]; vl[e] = lo[i * 8 + e]; }
    *(u16x8*)(th + off) = vh;
    *(u16x8*)(tl + off) = vl;
  }
}

// ---------------------------------------------------------------------------
// K1: p = squash(x @ Wp + bp) via split-bf16 MFMA.
// BM=64, BN=128, BK=64, 512 thr (8 waves, 4m x 2n), double-buffered 96 KB LDS.
// LDS buffer (ushort): A_hi[8kg][64row][8e] @0, A_lo @4096,
//                      B_hi[8kg][128col][8e] @8192, B_lo @16384
// ---------------------------------------------------------------------------
#define LDSBUF 24576

__global__ __launch_bounds__(512) void caps_primary(
    const float* __restrict__ x, const unsigned short* __restrict__ bth,
    const unsigned short* __restrict__ btl, const float* __restrict__ bp,
    float* __restrict__ p_out)
{
  __shared__ unsigned short lds[2 * LDSBUF];   // 96 KB
  const int tid  = threadIdx.x;
  const int lane = tid & 63;
  const int w    = tid >> 6;        // 0..7
  const int wm   = w >> 1;          // 0..3 -> rows wm*16..+15
  const int wn   = w & 1;           // 0..1 -> cols wn*64..+63
  const int row0 = blockIdx.x * 64;

  const int rowA = tid & 63;        // A staging: thread -> (kg=kgA, row=rowA)
  const int kgA  = tid >> 6;        // 0..7
  const float* xrow = x + (size_t)(row0 + rowA) * 1024;

  f32x4 acc[4];
#pragma unroll
  for (int j = 0; j < 4; ++j) acc[j] = (f32x4){0.f, 0.f, 0.f, 0.f};

  float4 a0, a1;
  u16x8 b0, b1, b2, b3;

#define STAGE_LOAD(kt) do { \
    const float* xp = xrow + (kt) * 64; \
    a0 = *(const float4*)(xp + kgA * 8); \
    a1 = *(const float4*)(xp + kgA * 8 + 4); \
    const unsigned short* bh_ = bth + (size_t)(kt) * 8192; \
    const unsigned short* bl_ = btl + (size_t)(kt) * 8192; \
    b0 = *(const u16x8*)(bh_ + (size_t)tid * 8); \
    b1 = *(const u16x8*)(bh_ + (size_t)(512 + tid) * 8); \
    b2 = *(const u16x8*)(bl_ + (size_t)tid * 8); \
    b3 = *(const u16x8*)(bl_ + (size_t)(512 + tid) * 8); \
  } while (0)

#define STAGE_WRITE(bufi) do { \
    u16x8 h0, l0; \
    cvt8(a0, a1, h0, l0); \
    unsigned short* B = lds + (bufi) * LDSBUF; \
    *(u16x8*)(B + kgA * 512 + rowA * 8) = h0; \
    *(u16x8*)(B + 4096 + kgA * 512 + rowA * 8) = l0; \
    *(u16x8*)(B + 8192  + tid * 8) = b0; \
    *(u16x8*)(B + 8192  + (512 + tid) * 8) = b1; \
    *(u16x8*)(B + 16384 + tid * 8) = b2; \
    *(u16x8*)(B + 16384 + (512 + tid) * 8) = b3; \
  } while (0)

#define COMPUTE(bufi) do { \
    const unsigned short* B = lds + (bufi) * LDSBUF; \
    _Pragma("unroll") \
    for (int s = 0; s < 2; ++s) { \
      const int kg = s * 4 + (lane >> 4); \
      const int rA = wm * 16 + (lane & 15); \
      const int cB = wn * 64 + (lane & 15); \
      bf16x8 ah = *(const bf16x8*)(B + kg * 512 + rA * 8); \
      bf16x8 al = *(const bf16x8*)(B + 4096 + kg * 512 + rA * 8); \
      _Pragma("unroll") \
      for (int nf = 0; nf < 4; ++nf) { \
        bf16x8 bh  = *(const bf16x8*)(B + 8192  + kg * 1024 + (cB + nf * 16) * 8); \
        bf16x8 blo = *(const bf16x8*)(B + 16384 + kg * 1024 + (cB + nf * 16) * 8); \
        acc[nf] = __builtin_amdgcn_mfma_f32_16x16x32_bf16(ah, bh,  acc[nf], 0, 0, 0); \
        acc[nf] = __builtin_amdgcn_mfma_f32_16x16x32_bf16(ah, blo, acc[nf], 0, 0, 0); \
        acc[nf] = __builtin_amdgcn_mfma_f32_16x16x32_bf16(al, bh,  acc[nf], 0, 0, 0); \
      } \
    } \
  } while (0)

  STAGE_LOAD(0);
  STAGE_WRITE(0);
  __syncthreads();
  for (int kt = 0; kt < 16; ++kt) {
    const int cur = kt & 1;
    if (kt < 15) STAGE_LOAD(kt + 1);
    COMPUTE(cur);
    if (kt < 15) STAGE_WRITE(cur ^ 1);
    __syncthreads();
  }

  // epilogue: bias + per-capsule squash (capsule == one 16-wide n-frag)
  const int ln = lane & 15, l4 = lane >> 4;
  float bpv[4];
#pragma unroll
  for (int nf = 0; nf < 4; ++nf) bpv[nf] = bp[wn * 64 + nf * 16 + ln];
#pragma unroll
  for (int nf = 0; nf < 4; ++nf)
#pragma unroll
    for (int r = 0; r < 4; ++r) {
      float val = acc[nf][r] + bpv[nf];
      float sq = val * val;
      sq += __shfl_xor(sq, 1); sq += __shfl_xor(sq, 2);
      sq += __shfl_xor(sq, 4); sq += __shfl_xor(sq, 8);
      float sc = (sq / (1.f + sq)) / sqrtf(sq + 1e-8f);
      p_out[(size_t)(row0 + wm * 16 + l4 * 4 + r) * 128 +
            wn * 64 + nf * 16 + ln] = val * sc;
    }
#undef STAGE_LOAD
#undef STAGE_WRITE
#undef COMPUTE
}

// ---------------------------------------------------------------------------
// K2: u_hat in registers + routing. 512 thr = 8 waves = 4 pairs.
// Wave pair p handles rows p*4..p*4+3; wave half h owns o in [h*256,(h+1)*256).
// Lane: o = h*256 + lane*4 + j.  u[4 rows][8 caps][4 j] = 128 VGPR.
// ---------------------------------------------------------------------------
__global__ __launch_bounds__(512) void caps_routing(
    const float* __restrict__ p_in, const float* __restrict__ W,
    float* __restrict__ out)
{
  __shared__ float ps[16][128];         // 8 KB
  __shared__ float wsh[8192];           // 32 KB: one capsule's W[n] [16d][512o]
  __shared__ float x1[4][2][4];         // ss exchange
  __shared__ float x2[4][2][4][8];      // agreement exchange
  const int tid  = threadIdx.x;
  const int lane = tid & 63;
  const int w    = tid >> 6;
  const int pair = w >> 1, half = w & 1;
  const int row0  = blockIdx.x * 16;
  const int rbase = pair * 4;
  const int obase = half * 256 + lane * 4;

  { int r = tid >> 5, q = tid & 31;
    *(float4*)&ps[r][q * 4] = *(const float4*)(p_in + (size_t)(row0 + r) * 128 + q * 4); }

  float u[4][8][4];
#pragma unroll
  for (int r = 0; r < 4; ++r)
#pragma unroll
    for (int n = 0; n < 8; ++n)
#pragma unroll
      for (int j = 0; j < 4; ++j) u[r][n][j] = 0.f;

  float4 wr0 = *(const float4*)(W + tid * 4);
  float4 wr1 = *(const float4*)(W + tid * 4 + 2048);
  float4 wr2 = *(const float4*)(W + tid * 4 + 4096);
  float4 wr3 = *(const float4*)(W + tid * 4 + 6144);

#pragma unroll
  for (int n = 0; n < 8; ++n) {
    *(float4*)&wsh[tid * 4]        = wr0;
    *(float4*)&wsh[tid * 4 + 2048] = wr1;
    *(float4*)&wsh[tid * 4 + 4096] = wr2;
    *(float4*)&wsh[tid * 4 + 6144] = wr3;
    __syncthreads();
    if (n < 7) {
      const float* Wn = W + (size_t)(n + 1) * 8192;
      wr0 = *(const float4*)(Wn + tid * 4);
      wr1 = *(const float4*)(Wn + tid * 4 + 2048);
      wr2 = *(const float4*)(Wn + tid * 4 + 4096);
      wr3 = *(const float4*)(Wn + tid * 4 + 6144);
    }
#pragma unroll
    for (int d4 = 0; d4 < 4; ++d4) {
      float pa[4][4];
#pragma unroll
      for (int r = 0; r < 4; ++r) {
        float4 pv = *(const float4*)&ps[rbase + r][n * 16 + d4 * 4];
        pa[r][0] = pv.x; pa[r][1] = pv.y; pa[r][2] = pv.z; pa[r][3] = pv.w;
      }
#pragma unroll
      for (int dd = 0; dd < 4; ++dd) {
        float4 wv4 = *(const float4*)&wsh[(d4 * 4 + dd) * 512 + obase];
        float wv[4] = {wv4.x, wv4.y, wv4.z, wv4.w};
#pragma unroll
        for (int r = 0; r < 4; ++r)
#pragma unroll
          for (int j = 0; j < 4; ++j)
            u[r][n][j] = fmaf(pa[r][dd], wv[j], u[r][n][j]);
      }
    }
    if (n < 7) __syncthreads();
  }

  float bl[4][8];
#pragma unroll
  for (int r = 0; r < 4; ++r)
#pragma unroll
    for (int n = 0; n < 8; ++n) bl[r][n] = 0.f;
  float vv[4][4];

#pragma unroll
  for (int it = 0; it < 3; ++it) {
    float c[4][8];
#pragma unroll
    for (int r = 0; r < 4; ++r) {
      float mx = bl[r][0];
#pragma unroll
      for (int n = 1; n < 8; ++n) mx = fmaxf(mx, bl[r][n]);
      float Z = 0.f;
#pragma unroll
      for (int n = 0; n < 8; ++n) { c[r][n] = expf(bl[r][n] - mx); Z += c[r][n]; }
      float iz = 1.f / Z;
#pragma unroll
      for (int n = 0; n < 8; ++n) c[r][n] *= iz;
    }
    float s[4][4];
#pragma unroll
    for (int r = 0; r < 4; ++r)
#pragma unroll
      for (int j = 0; j < 4; ++j) s[r][j] = 0.f;
#pragma unroll
    for (int r = 0; r < 4; ++r)
#pragma unroll
      for (int n = 0; n < 8; ++n)
#pragma unroll
        for (int j = 0; j < 4; ++j) s[r][j] = fmaf(c[r][n], u[r][n][j], s[r][j]);
    float ss[4];
#pragma unroll
    for (int r = 0; r < 4; ++r)
      ss[r] = s[r][0]*s[r][0] + s[r][1]*s[r][1] + s[r][2]*s[r][2] + s[r][3]*s[r][3];
#pragma unroll
    for (int off = 1; off < 64; off <<= 1) {
#pragma unroll
      for (int r = 0; r < 4; ++r) ss[r] += __shfl_xor(ss[r], off);
    }
    __syncthreads();                                  // protect x1/x2 reuse
    if (lane == 0) {
#pragma unroll
      for (int r = 0; r < 4; ++r) x1[pair][half][r] = ss[r];
    }
    __syncthreads();
#pragma unroll
    for (int r = 0; r < 4; ++r) {
      float st = x1[pair][0][r] + x1[pair][1][r];
      float sc = (st / (1.f + st)) / sqrtf(st + 1e-8f);
#pragma unroll
      for (int j = 0; j < 4; ++j) vv[r][j] = s[r][j] * sc;
    }
    if (it < 2) {
      float t[4][8];
#pragma unroll
      for (int r = 0; r < 4; ++r)
#pragma unroll
        for (int n = 0; n < 8; ++n) {
          float a = u[r][n][0] * vv[r][0] + u[r][n][1] * vv[r][1]
                  + u[r][n][2] * vv[r][2] + u[r][n][3] * vv[r][3];
          t[r][n] = a;
        }
#pragma unroll
      for (int off = 1; off < 64; off <<= 1) {
#pragma unroll
        for (int r = 0; r < 4; ++r)
#pragma unroll
          for (int n = 0; n < 8; ++n) t[r][n] += __shfl_xor(t[r][n], off);
      }
      if (lane == 0) {
#pragma unroll
        for (int r = 0; r < 4; ++r)
#pragma unroll
          for (int n = 0; n < 8; ++n) x2[pair][half][r][n] = t[r][n];
      }
      __syncthreads();
#pragma unroll
      for (int r = 0; r < 4; ++r)
#pragma unroll
        for (int n = 0; n < 8; ++n)
          bl[r][n] += x2[pair][0][r][n] + x2[pair][1][r][n];
    }
  }

#pragma unroll
  for (int r = 0; r < 4; ++r)
    *(float4*)(out + (size_t)(row0 + rbase + r) * 512 + obase) =
        make_float4(vv[r][0], vv[r][1], vv[r][2], vv[r][3]);
}

extern "C" void kernel_launch(void* const* d_in, const int* in_sizes, int n_in,
                              void* d_out, int out_size, void* d_ws, size_t ws_size,
                              hipStream_t stream) {
  (void)in_sizes; (void)n_in; (void)out_size; (void)ws_size;
  const float* x  = (const float*)d_in[0];
  const float* Wp = (const float*)d_in[1];
  const float* bp = (const float*)d_in[2];
  const float* W  = (const float*)d_in[3];
  // d_in[4] = n_routing (fixed = 3)
  float* p_ws = (float*)d_ws;                                   // 8 MB
  unsigned short* th = (unsigned short*)((char*)d_ws + (8u << 20));  // 256 KB
  unsigned short* tl = th + 131072;                             // 256 KB
  float* outp = (float*)d_out;

  caps_prep<<<16, 256, 0, stream>>>(Wp, th, tl);
  caps_primary<<<256, 512, 0, stream>>>(x, th, tl, bp, p_ws);
  caps_routing<<<1024, 512, 0, stream>>>(p_ws, W, outp);
}

// Round 4
// 99.494 us; speedup vs baseline: 5.4004x; 5.4004x over previous
//
#include <hip/hip_runtime.h>
#include <math.h>

typedef __attribute__((ext_vector_type(8))) short bf16x8;
typedef __attribute__((ext_vector_type(8))) unsigned short u16x8;
typedef __attribute__((ext_vector_type(4))) float f32x4;

__device__ __forceinline__ unsigned short f2bf(float f) {
  unsigned u = __float_as_uint(f);
  return (unsigned short)((u + 0x7FFFu + ((u >> 16) & 1u)) >> 16);
}
__device__ __forceinline__ float bf2f(unsigned short h) {
  return __uint_as_float(((unsigned)h) << 16);
}
__device__ __forceinline__ void cvt8(const float4& a, const float4& b,
                                     u16x8& h, u16x8& l) {
  float f[8] = {a.x, a.y, a.z, a.w, b.x, b.y, b.z, b.w};
#pragma unroll
  for (int i = 0; i < 8; ++i) {
    unsigned short hh = f2bf(f[i]);
    h[i] = hh;
    l[i] = f2bf(f[i] - bf2f(hh));
  }
}

// pair tables: 36 (m,n) pairs with m<=n
__device__ const int PM36[36] = {0,0,0,0,0,0,0,0, 1,1,1,1,1,1,1, 2,2,2,2,2,2,
                                 3,3,3,3,3, 4,4,4,4, 5,5,5, 6,6, 7};
__device__ const int PN36[36] = {0,1,2,3,4,5,6,7, 1,2,3,4,5,6,7, 2,3,4,5,6,7,
                                 3,4,5,6,7, 4,5,6,7, 5,6,7, 6,7, 7};
__device__ __forceinline__ constexpr int gidx(int a, int b) {
  int m = a < b ? a : b, n = a < b ? b : a;
  return m * 8 - (m * (m - 1)) / 2 + (n - m);
}

// ---------------------------------------------------------------------------
// K0a: transpose+split Wp [1024][128] fp32 -> k-major bf16 tiles
//      th/tl layout: [kt 16][kg 8][col 128][e 8]   (k = kt*64+kg*8+e)
// ---------------------------------------------------------------------------
__global__ __launch_bounds__(256) void caps_prep(
    const float* __restrict__ Wp, unsigned short* __restrict__ th,
    unsigned short* __restrict__ tl)
{
  __shared__ float tile[64][128];
  const int t = threadIdx.x, b = blockIdx.x;
  const float* src = Wp + (size_t)b * 64 * 128;
#pragma unroll
  for (int i = 0; i < 8; ++i) {
    int j = t + i * 256;
    int kk = j >> 5, q = j & 31;
    *(float4*)&tile[kk][q * 4] = *(const float4*)(src + kk * 128 + q * 4);
  }
  __syncthreads();
  const int col = t >> 1, kg0 = (t & 1) * 4;
  unsigned short hi[32], lo[32];
#pragma unroll
  for (int kk = 0; kk < 32; ++kk) {
    float v = tile[kg0 * 8 + kk][col];
    unsigned short h = f2bf(v);
    hi[kk] = h;
    lo[kk] = f2bf(v - bf2f(h));
  }
#pragma unroll
  for (int i = 0; i < 4; ++i) {
    size_t off = (size_t)b * 8192 + (size_t)(kg0 + i) * 1024 + (size_t)col * 8;
    u16x8 vh, vl;
#pragma unroll
    for (int e = 0; e < 8; ++e) { vh[e] = hi[i * 8 + e]; vl[e] = lo[i * 8 + e]; }
    *(u16x8*)(th + off) = vh;
    *(u16x8*)(tl + off) = vl;
  }
}

// ---------------------------------------------------------------------------
// K0b: split W_flat [128][512] fp32 -> [kt 2][kg 8][col 512][e 8] bf16 hi/lo
// ---------------------------------------------------------------------------
__global__ __launch_bounds__(256) void caps_prep2(
    const float* __restrict__ W, unsigned short* __restrict__ th,
    unsigned short* __restrict__ tl)
{
  int t = blockIdx.x * 256 + threadIdx.x;   // 4096 threads, 8192 chunks
#pragma unroll
  for (int h = 0; h < 2; ++h) {
    int c = t + h * 4096;
    int kt = c >> 12, rem = c & 4095;
    int kg = rem >> 9, col = rem & 511;
    int kbase = kt * 64 + kg * 8;
    u16x8 vh, vl;
#pragma unroll
    for (int e = 0; e < 8; ++e) {
      float v = W[(size_t)(kbase + e) * 512 + col];
      unsigned short hh = f2bf(v);
      vh[e] = hh;
      vl[e] = f2bf(v - bf2f(hh));
    }
    size_t off = ((size_t)(kt * 8 + kg) * 512 + col) * 8;
    *(u16x8*)(th + off) = vh;
    *(u16x8*)(tl + off) = vl;
  }
}

// ---------------------------------------------------------------------------
// K0c: Gram M[a][b] = sum_o Wf[a][o]*Wf[b][o]   (Wf = W as [128][512])
// ---------------------------------------------------------------------------
__global__ __launch_bounds__(256) void caps_gram(
    const float* __restrict__ W, float* __restrict__ M)
{
  int a = blockIdx.x * 16 + (threadIdx.x >> 4);
  int b = blockIdx.y * 16 + (threadIdx.x & 15);
  const float* wa = W + (size_t)a * 512;
  const float* wb = W + (size_t)b * 512;
  float acc = 0.f;
#pragma unroll 4
  for (int o = 0; o < 512; o += 4) {
    float4 x = *(const float4*)(wa + o);
    float4 y = *(const float4*)(wb + o);
    acc += x.x * y.x + x.y * y.y + x.z * y.z + x.w * y.w;
  }
  M[a * 128 + b] = acc;
}

// ---------------------------------------------------------------------------
// K1: p = squash(x @ Wp + bp) via split-bf16 MFMA.  (unchanged, verified)
// ---------------------------------------------------------------------------
#define LDSBUF 24576

__global__ __launch_bounds__(512) void caps_primary(
    const float* __restrict__ x, const unsigned short* __restrict__ bth,
    const unsigned short* __restrict__ btl, const float* __restrict__ bp,
    float* __restrict__ p_out)
{
  __shared__ unsigned short lds[2 * LDSBUF];   // 96 KB
  const int tid  = threadIdx.x;
  const int lane = tid & 63;
  const int w    = tid >> 6;
  const int wm   = w >> 1;
  const int wn   = w & 1;
  const int row0 = blockIdx.x * 64;

  const int rowA = tid & 63;
  const int kgA  = tid >> 6;
  const float* xrow = x + (size_t)(row0 + rowA) * 1024;

  f32x4 acc[4];
#pragma unroll
  for (int j = 0; j < 4; ++j) acc[j] = (f32x4){0.f, 0.f, 0.f, 0.f};

  float4 a0, a1;
  u16x8 b0, b1, b2, b3;

#define STAGE_LOAD(kt) do { \
    const float* xp = xrow + (kt) * 64; \
    a0 = *(const float4*)(xp + kgA * 8); \
    a1 = *(const float4*)(xp + kgA * 8 + 4); \
    const unsigned short* bh_ = bth + (size_t)(kt) * 8192; \
    const unsigned short* bl_ = btl + (size_t)(kt) * 8192; \
    b0 = *(const u16x8*)(bh_ + (size_t)tid * 8); \
    b1 = *(const u16x8*)(bh_ + (size_t)(512 + tid) * 8); \
    b2 = *(const u16x8*)(bl_ + (size_t)tid * 8); \
    b3 = *(const u16x8*)(bl_ + (size_t)(512 + tid) * 8); \
  } while (0)

#define STAGE_WRITE(bufi) do { \
    u16x8 h0, l0; \
    cvt8(a0, a1, h0, l0); \
    unsigned short* B = lds + (bufi) * LDSBUF; \
    *(u16x8*)(B + kgA * 512 + rowA * 8) = h0; \
    *(u16x8*)(B + 4096 + kgA * 512 + rowA * 8) = l0; \
    *(u16x8*)(B + 8192  + tid * 8) = b0; \
    *(u16x8*)(B + 8192  + (512 + tid) * 8) = b1; \
    *(u16x8*)(B + 16384 + tid * 8) = b2; \
    *(u16x8*)(B + 16384 + (512 + tid) * 8) = b3; \
  } while (0)

#define COMPUTE(bufi) do { \
    const unsigned short* B = lds + (bufi) * LDSBUF; \
    _Pragma("unroll") \
    for (int s = 0; s < 2; ++s) { \
      const int kg = s * 4 + (lane >> 4); \
      const int rA = wm * 16 + (lane & 15); \
      const int cB = wn * 64 + (lane & 15); \
      bf16x8 ah = *(const bf16x8*)(B + kg * 512 + rA * 8); \
      bf16x8 al = *(const bf16x8*)(B + 4096 + kg * 512 + rA * 8); \
      _Pragma("unroll") \
      for (int nf = 0; nf < 4; ++nf) { \
        bf16x8 bh  = *(const bf16x8*)(B + 8192  + kg * 1024 + (cB + nf * 16) * 8); \
        bf16x8 blo = *(const bf16x8*)(B + 16384 + kg * 1024 + (cB + nf * 16) * 8); \
        acc[nf] = __builtin_amdgcn_mfma_f32_16x16x32_bf16(ah, bh,  acc[nf], 0, 0, 0); \
        acc[nf] = __builtin_amdgcn_mfma_f32_16x16x32_bf16(ah, blo, acc[nf], 0, 0, 0); \
        acc[nf] = __builtin_amdgcn_mfma_f32_16x16x32_bf16(al, bh,  acc[nf], 0, 0, 0); \
      } \
    } \
  } while (0)

  STAGE_LOAD(0);
  STAGE_WRITE(0);
  __syncthreads();
  for (int kt = 0; kt < 16; ++kt) {
    const int cur = kt & 1;
    if (kt < 15) STAGE_LOAD(kt + 1);
    COMPUTE(cur);
    if (kt < 15) STAGE_WRITE(cur ^ 1);
    __syncthreads();
  }

  const int ln = lane & 15, l4 = lane >> 4;
  float bpv[4];
#pragma unroll
  for (int nf = 0; nf < 4; ++nf) bpv[nf] = bp[wn * 64 + nf * 16 + ln];
#pragma unroll
  for (int nf = 0; nf < 4; ++nf)
#pragma unroll
    for (int r = 0; r < 4; ++r) {
      float val = acc[nf][r] + bpv[nf];
      float sq = val * val;
      sq += __shfl_xor(sq, 1); sq += __shfl_xor(sq, 2);
      sq += __shfl_xor(sq, 4); sq += __shfl_xor(sq, 8);
      float sc = (sq / (1.f + sq)) / sqrtf(sq + 1e-8f);
      p_out[(size_t)(row0 + wm * 16 + l4 * 4 + r) * 128 +
            wn * 64 + nf * 16 + ln] = val * sc;
    }
#undef STAGE_LOAD
#undef STAGE_WRITE
#undef COMPUTE
}

// ---------------------------------------------------------------------------
// K2: Gram-based routing. 256 thr = 4 waves; 64 rows/block (row = lane).
// Wave w computes pairs [w*9, w*9+9) of G for all 64 rows (M broadcast from
// LDS). Then wave 0 runs the 8-dim routing per row and emits cs = scale*c.
// Finally q[row] = cs[n]*p[row] written in-place over p.
// ---------------------------------------------------------------------------
__global__ __launch_bounds__(256, 1) void caps_route_g(
    const float* __restrict__ p_in, const float* __restrict__ Mg,
    float* __restrict__ qout)
{
  __shared__ float p_lds[128 * 66];   // transposed [k][row], pad 66
  __shared__ float M_lds[16384];
  __shared__ float G_lds[64 * 37];
  __shared__ float cs_lds[64 * 9];
  const int tid  = threadIdx.x;
  const int lane = tid & 63;
  const int w    = tid >> 6;
  const int row0 = blockIdx.x * 64;

  // stage p transposed: [k][row]
#pragma unroll
  for (int i = 0; i < 8; ++i) {
    int j = tid + i * 256;
    int r = j >> 5, c4 = j & 31;
    float4 v = *(const float4*)(p_in + (size_t)(row0 + r) * 128 + c4 * 4);
    p_lds[(c4 * 4 + 0) * 66 + r] = v.x;
    p_lds[(c4 * 4 + 1) * 66 + r] = v.y;
    p_lds[(c4 * 4 + 2) * 66 + r] = v.z;
    p_lds[(c4 * 4 + 3) * 66 + r] = v.w;
  }
#pragma unroll
  for (int i = 0; i < 16; ++i) {
    int j = tid + i * 256;
    *(float4*)&M_lds[j * 4] = *(const float4*)(Mg + j * 4);
  }
  __syncthreads();

  // G phase
  for (int i = 0; i < 9; ++i) {
    const int pi = w * 9 + i;
    const int m = PM36[pi], n = PN36[pi];
    float pm[16], pn[16];
#pragma unroll
    for (int j = 0; j < 16; ++j) pm[j] = p_lds[(m * 16 + j) * 66 + lane];
#pragma unroll
    for (int j = 0; j < 16; ++j) pn[j] = p_lds[(n * 16 + j) * 66 + lane];
    float acc = 0.f;
#pragma unroll
    for (int ii = 0; ii < 16; ++ii) {
      const float* Mr = &M_lds[(n * 16 + ii) * 128 + m * 16];
      float t = 0.f;
#pragma unroll
      for (int j4 = 0; j4 < 4; ++j4) {
        float4 mv = *(const float4*)(Mr + j4 * 4);
        t = fmaf(mv.x, pm[j4 * 4 + 0], t);
        t = fmaf(mv.y, pm[j4 * 4 + 1], t);
        t = fmaf(mv.z, pm[j4 * 4 + 2], t);
        t = fmaf(mv.w, pm[j4 * 4 + 3], t);
      }
      acc = fmaf(pn[ii], t, acc);
    }
    G_lds[lane * 37 + pi] = acc;
  }
  __syncthreads();

  if (w == 0) {
    float Gf[36];
#pragma unroll
    for (int j = 0; j < 36; ++j) Gf[j] = G_lds[lane * 37 + j];
    float bb[8] = {0.f, 0.f, 0.f, 0.f, 0.f, 0.f, 0.f, 0.f};
    float cs[8];
#pragma unroll
    for (int it = 0; it < 3; ++it) {
      float mx = bb[0];
#pragma unroll
      for (int n = 1; n < 8; ++n) mx = fmaxf(mx, bb[n]);
      float e[8], Z = 0.f;
#pragma unroll
      for (int n = 0; n < 8; ++n) { e[n] = expf(bb[n] - mx); Z += e[n]; }
      float inv = 1.f / Z;
      float c[8];
#pragma unroll
      for (int n = 0; n < 8; ++n) c[n] = e[n] * inv;
      float t[8] = {0.f, 0.f, 0.f, 0.f, 0.f, 0.f, 0.f, 0.f};
#pragma unroll
      for (int n = 0; n < 8; ++n)
#pragma unroll
        for (int m2 = 0; m2 < 8; ++m2)
          t[n] = fmaf(Gf[gidx(n, m2)], c[m2], t[n]);
      float ss = 0.f;
#pragma unroll
      for (int n = 0; n < 8; ++n) ss = fmaf(c[n], t[n], ss);
      float scale = (ss / (1.f + ss)) / sqrtf(ss + 1e-8f);
      if (it < 2) {
#pragma unroll
        for (int n = 0; n < 8; ++n) bb[n] += scale * t[n];
      } else {
#pragma unroll
        for (int n = 0; n < 8; ++n) cs[n] = scale * c[n];
      }
    }
#pragma unroll
    for (int n = 0; n < 8; ++n) cs_lds[lane * 9 + n] = cs[n];
  }
  __syncthreads();

  // q = cs[n] * p  (read p from global again, coalesced; in-place write ok:
  // this block owns rows [row0,row0+64) exclusively and staged them already)
#pragma unroll
  for (int i = 0; i < 8; ++i) {
    int j = tid + i * 256;
    int r = j >> 5, c4 = j & 31;
    float4 pv = *(const float4*)(p_in + (size_t)(row0 + r) * 128 + c4 * 4);
    float csv = cs_lds[r * 9 + (c4 >> 2)];
    *(float4*)(qout + (size_t)(row0 + r) * 128 + c4 * 4) =
        make_float4(pv.x * csv, pv.y * csv, pv.z * csv, pv.w * csv);
  }
}

// ---------------------------------------------------------------------------
// K3: v = q @ Wflat  [16384,128]x[128,512] split-bf16 MFMA.
// BM=64, BN=128, K=128 (2 steps of 64). 512 thr, single 48 KB LDS buffer.
// ---------------------------------------------------------------------------
__global__ __launch_bounds__(512) void caps_vout(
    const float* __restrict__ q, const unsigned short* __restrict__ bth,
    const unsigned short* __restrict__ btl, float* __restrict__ out)
{
  __shared__ unsigned short lds[LDSBUF];   // 48 KB
  const int tid  = threadIdx.x;
  const int lane = tid & 63;
  const int w    = tid >> 6;
  const int wm   = w >> 1;
  const int wn   = w & 1;
  const int row0 = blockIdx.x * 64;
  const int col0 = blockIdx.y * 128;

  const int rowA = tid & 63;
  const int kgA  = tid >> 6;
  const float* qrow = q + (size_t)(row0 + rowA) * 128;

  f32x4 acc[4];
#pragma unroll
  for (int j = 0; j < 4; ++j) acc[j] = (f32x4){0.f, 0.f, 0.f, 0.f};

  float4 a0, a1;
  u16x8 b0, b1, b2, b3;

#define VSTAGE_LOAD(kt) do { \
    const float* xp = qrow + (kt) * 64; \
    a0 = *(const float4*)(xp + kgA * 8); \
    a1 = *(const float4*)(xp + kgA * 8 + 4); \
    const int kg0 = tid >> 7, col = tid & 127; \
    const size_t s0 = ((size_t)((kt) * 8 + kg0) * 512 + col0 + col) * 8; \
    const size_t s1 = ((size_t)((kt) * 8 + 4 + kg0) * 512 + col0 + col) * 8; \
    b0 = *(const u16x8*)(bth + s0); \
    b1 = *(const u16x8*)(bth + s1); \
    b2 = *(const u16x8*)(btl + s0); \
    b3 = *(const u16x8*)(btl + s1); \
  } while (0)

#define VSTAGE_WRITE() do { \
    u16x8 h0, l0; \
    cvt8(a0, a1, h0, l0); \
    *(u16x8*)(lds + kgA * 512 + rowA * 8) = h0; \
    *(u16x8*)(lds + 4096 + kgA * 512 + rowA * 8) = l0; \
    *(u16x8*)(lds + 8192  + tid * 8) = b0; \
    *(u16x8*)(lds + 12288 + tid * 8) = b1; \
    *(u16x8*)(lds + 16384 + tid * 8) = b2; \
    *(u16x8*)(lds + 20480 + tid * 8) = b3; \
  } while (0)

#define VCOMPUTE() do { \
    _Pragma("unroll") \
    for (int s = 0; s < 2; ++s) { \
      const int kg = s * 4 + (lane >> 4); \
      const int rA = wm * 16 + (lane & 15); \
      const int cB = wn * 64 + (lane & 15); \
      bf16x8 ah = *(const bf16x8*)(lds + kg * 512 + rA * 8); \
      bf16x8 al = *(const bf16x8*)(lds + 4096 + kg * 512 + rA * 8); \
      _Pragma("unroll") \
      for (int nf = 0; nf < 4; ++nf) { \
        bf16x8 bh  = *(const bf16x8*)(lds + 8192  + kg * 1024 + (cB + nf * 16) * 8); \
        bf16x8 blo = *(const bf16x8*)(lds + 16384 + kg * 1024 + (cB + nf * 16) * 8); \
        acc[nf] = __builtin_amdgcn_mfma_f32_16x16x32_bf16(ah, bh,  acc[nf], 0, 0, 0); \
        acc[nf] = __builtin_amdgcn_mfma_f32_16x16x32_bf16(ah, blo, acc[nf], 0, 0, 0); \
        acc[nf] = __builtin_amdgcn_mfma_f32_16x16x32_bf16(al, bh,  acc[nf], 0, 0, 0); \
      } \
    } \
  } while (0)

  VSTAGE_LOAD(0);
  VSTAGE_WRITE();
  __syncthreads();
  VSTAGE_LOAD(1);
  VCOMPUTE();
  __syncthreads();
  VSTAGE_WRITE();
  __syncthreads();
  VCOMPUTE();

  const int ln = lane & 15, l4 = lane >> 4;
#pragma unroll
  for (int nf = 0; nf < 4; ++nf)
#pragma unroll
    for (int r = 0; r < 4; ++r)
      out[(size_t)(row0 + wm * 16 + l4 * 4 + r) * 512 +
          col0 + wn * 64 + nf * 16 + ln] = acc[nf][r];
#undef VSTAGE_LOAD
#undef VSTAGE_WRITE
#undef VCOMPUTE
}

extern "C" void kernel_launch(void* const* d_in, const int* in_sizes, int n_in,
                              void* d_out, int out_size, void* d_ws, size_t ws_size,
                              hipStream_t stream) {
  (void)in_sizes; (void)n_in; (void)out_size; (void)ws_size;
  const float* x  = (const float*)d_in[0];
  const float* Wp = (const float*)d_in[1];
  const float* bp = (const float*)d_in[2];
  const float* W  = (const float*)d_in[3];
  // d_in[4] = n_routing (fixed = 3)
  char* ws = (char*)d_ws;
  float* p_ws = (float*)ws;                                   // 8 MB (p, then q in-place)
  unsigned short* th1 = (unsigned short*)(ws + 8388608);      // 256 KB
  unsigned short* tl1 = (unsigned short*)(ws + 8650752);      // 256 KB
  unsigned short* th2 = (unsigned short*)(ws + 8912896);      // 128 KB
  unsigned short* tl2 = (unsigned short*)(ws + 9043968);      // 128 KB
  float* Mws = (float*)(ws + 9175040);                        // 64 KB
  float* outp = (float*)d_out;

  caps_prep<<<16, 256, 0, stream>>>(Wp, th1, tl1);
  caps_prep2<<<16, 256, 0, stream>>>(W, th2, tl2);
  caps_gram<<<dim3(8, 8), 256, 0, stream>>>(W, Mws);
  caps_primary<<<256, 512, 0, stream>>>(x, th1, tl1, bp, p_ws);
  caps_route_g<<<256, 256, 0, stream>>>(p_ws, Mws, p_ws);
  caps_vout<<<dim3(256, 4), 512, 0, stream>>>(p_ws, th2, tl2, outp);
}